// Round 8
// baseline (14.140 us; speedup 1.0000x reference)
//
#include <hip/hip_runtime.h>
#include <math.h>

namespace {
constexpr int NFACES = 384;
constexpr int IMG    = 256;
constexpr int CROP0  = 16;
constexpr int CROPN  = 224;
constexpr int NPIX   = CROPN * CROPN;       // 50176
constexpr int TILE   = 8;                   // 8x8 pixel tiles
constexpr int TILES_X = CROPN / TILE;       // 28
constexpr int NTILES  = TILES_X * TILES_X;  // 784
constexpr int NF4     = NFACES * 9 / 4;     // 864 float4 per input array
constexpr float INV_SIGMA = 1e5f;
constexpr float INV_GAMMA = 1e5f;
constexpr float EPSV  = 1e-4f;
constexpr float NEARV = 0.1f;
constexpr float FARV  = 100.0f;
constexpr float INV_FMN = 1.0f / (FARV - NEARV);
constexpr float THRESH = 1.1512915464633e-04f;  // SIGMA*ln(1/DIST_EPS - 1)
constexpr float RADIUS = 0.0118f;               // sqrt(THRESH) + margin
}

__device__ __forceinline__ float clamp01(float x) {
  return fminf(fmaxf(x, 0.0f), 1.0f);
}

// One block = one 8x8 tile, 256 threads (4 waves). Each wave: 16 pixels,
// 4-way face split, PRIVATE ballot-compacted face list (wave-local LDS, no
// barrier after binning). Single __syncthreads: staging -> binning.
__global__ __launch_bounds__(256) void softras_fused(
    const float* __restrict__ g_faces, const float* __restrict__ g_tex,
    float* __restrict__ d_out) {
  __shared__ __align__(16) float sface[NFACES * 9];   // 13824 B
  __shared__ __align__(16) float stex[NFACES * 9];    // 13824 B
  __shared__ unsigned short slist[4 * NFACES];        // 3072 B (per-wave)

  int tid  = threadIdx.x;
  int w    = tid >> 6;           // wave 0..3
  int lane = tid & 63;

  // ---- coalesced raw staging ----
  {
    const float4* gf4 = reinterpret_cast<const float4*>(g_faces);
    const float4* gt4 = reinterpret_cast<const float4*>(g_tex);
    float4* sf4 = reinterpret_cast<float4*>(sface);
    float4* st4 = reinterpret_cast<float4*>(stex);
    for (int i = tid; i < NF4; i += 256) {
      sf4[i] = gf4[i];
      st4[i] = gt4[i];
    }
  }

  int tileX = blockIdx.x % TILES_X;
  int tileY = blockIdx.x / TILES_X;
  float x_lo = (2.0f * (tileX * TILE + CROP0) + 1.0f) * (1.0f / IMG) - 1.0f;
  float x_hi = x_lo + (TILE - 1) * (2.0f / IMG);
  float y_hi = (2.0f * (IMG - 1 - (tileY * TILE + CROP0)) + 1.0f) * (1.0f / IMG) - 1.0f;
  float y_lo = y_hi - (TILE - 1) * (2.0f / IMG);

  __syncthreads();   // staging complete (only barrier in the kernel)

  // ---- binning from LDS into this wave's PRIVATE list ----
  unsigned short* mylist = &slist[w * NFACES];
  unsigned long long lm = (1ull << lane) - 1ull;
  int L = 0;
  #pragma unroll
  for (int r = 0; r < 6; ++r) {
    int f = r * 64 + lane;
    const float* fv = &sface[f * 9];
    float fx0 = fv[0], fy0 = fv[1];
    float fx1 = fv[3], fy1 = fv[4];
    float fx2 = fv[6], fy2 = fv[7];
    float bxmin = fminf(fx0, fminf(fx1, fx2)) - RADIUS;
    float bxmax = fmaxf(fx0, fmaxf(fx1, fx2)) + RADIUS;
    float bymin = fminf(fy0, fminf(fy1, fy2)) - RADIUS;
    float bymax = fmaxf(fy0, fmaxf(fy1, fy2)) + RADIUS;
    bool pred = (bxmin <= x_hi) && (bxmax >= x_lo) &&
                (bymin <= y_hi) && (bymax >= y_lo);
    unsigned long long bal = __ballot(pred);
    if (pred) mylist[L + __popcll(bal & lm)] = (unsigned short)f;
    L += __popcll(bal);
  }
  // wave-local ds write->read: compiler-inserted lgkmcnt suffices, no barrier

  // ---- per-pixel accumulation: wave w owns pixels w*16..w*16+15 ----
  int s  = lane >> 4;                 // face sub-chunk 0..3
  int p  = (w << 4) | (lane & 15);    // pixel in tile 0..63
  int px = p & 7, py = p >> 3;
  float qx = x_lo + px * (2.0f / IMG);
  float qy = y_hi - py * (2.0f / IMG);

  float m = EPSV;
  float sum_ew = 0.0f, sum_r = 0.0f, sum_g = 0.0f, sum_b = 0.0f;
  float aprod = 1.0f;

  for (int j = s; j < L; j += 4) {
    int f = mylist[j];
    const float* fv = &sface[f * 9];
    const float* tx = &stex[f * 9];
    float x0 = fv[0], y0 = fv[1], z0 = fv[2];
    float x1 = fv[3], y1 = fv[4], z1 = fv[5];
    float x2 = fv[6], y2 = fv[7], z2 = fv[8];

    float den = (y1 - y2) * (x0 - x2) + (x2 - x1) * (y0 - y2);
    if (fabsf(den) < 1e-10f) den = (den < 0.0f) ? -1e-10f : 1e-10f;
    float dinv = __builtin_amdgcn_rcpf(den);

    float qa2x = qx - x2, qa2y = qy - y2;
    float w0 = ((y1 - y2) * qa2x + (x2 - x1) * qa2y) * dinv;
    float w1 = ((y2 - y0) * qa2x + (x0 - x2) * qa2y) * dinv;
    float w2 = 1.0f - w0 - w1;
    bool inside = (w0 >= 0.0f) && (w1 >= 0.0f) && (w2 >= 0.0f);

    float qa0x = qx - x0, qa0y = qy - y0;
    float qa1x = qx - x1, qa1y = qy - y1;

    float ex = x1 - x0, ey = y1 - y0;
    float il = __builtin_amdgcn_rcpf(fmaxf(ex * ex + ey * ey, 1e-12f));
    float tt = clamp01((qa0x * ex + qa0y * ey) * il);
    float dx = qa0x - tt * ex, dy = qa0y - tt * ey;
    float d2min = dx * dx + dy * dy;

    ex = x2 - x1; ey = y2 - y1;
    il = __builtin_amdgcn_rcpf(fmaxf(ex * ex + ey * ey, 1e-12f));
    tt = clamp01((qa1x * ex + qa1y * ey) * il);
    dx = qa1x - tt * ex; dy = qa1y - tt * ey;
    d2min = fminf(d2min, dx * dx + dy * dy);

    ex = x0 - x2; ey = y0 - y2;
    il = __builtin_amdgcn_rcpf(fmaxf(ex * ex + ey * ey, 1e-12f));
    tt = clamp01((qa2x * ex + qa2y * ey) * il);
    dx = qa2x - tt * ex; dy = qa2y - tt * ey;
    d2min = fminf(d2min, dx * dx + dy * dy);

    bool contrib = inside || (d2min <= THRESH);

    float wc0 = clamp01(w0), wc1 = clamp01(w1), wc2 = clamp01(w2);
    float invs = __builtin_amdgcn_rcpf(fmaxf(wc0 + wc1 + wc2, 1e-12f));
    wc0 *= invs; wc1 *= invs; wc2 *= invs;

    float zden = wc0 * __builtin_amdgcn_rcpf(z0) +
                 wc1 * __builtin_amdgcn_rcpf(z1) +
                 wc2 * __builtin_amdgcn_rcpf(z2);
    float zp = __builtin_amdgcn_rcpf(fmaxf(zden, 1e-12f));
    bool valid = contrib && (zp >= NEARV) && (zp <= FARV);
    float zn = (FARV - zp) * INV_FMN;
    float zns = valid ? zn : 0.0f;

    float e = __expf(-d2min * INV_SIGMA);
    float r1pe = __builtin_amdgcn_rcpf(1.0f + e);
    float Dp = inside ? r1pe : e * r1pe;   // stable sigmoid

    float mnew = fmaxf(m, zns);
    float cor = __expf((m - mnew) * INV_GAMMA);
    float ew = valid ? Dp * __expf((zns - mnew) * INV_GAMMA) : 0.0f;

    float cr = wc0 * tx[0] + wc1 * tx[3] + wc2 * tx[6];
    float cg = wc0 * tx[1] + wc1 * tx[4] + wc2 * tx[7];
    float cb = wc0 * tx[2] + wc1 * tx[5] + wc2 * tx[8];

    sum_ew = sum_ew * cor + ew;
    sum_r  = sum_r  * cor + ew * cr;
    sum_g  = sum_g  * cor + ew * cg;
    sum_b  = sum_b  * cor + ew * cb;
    aprod *= contrib ? (1.0f - Dp) : 1.0f;
    m = mnew;
  }

  // ---- merge the 4 face sub-chunks (lane bits 4..5) ----
  #pragma unroll
  for (int mask = 16; mask <= 32; mask <<= 1) {
    float mo = __shfl_xor(m, mask);
    float so = __shfl_xor(sum_ew, mask);
    float ro = __shfl_xor(sum_r, mask);
    float go = __shfl_xor(sum_g, mask);
    float bo = __shfl_xor(sum_b, mask);
    float ao = __shfl_xor(aprod, mask);
    float mn = fmaxf(m, mo);
    float c1 = __expf((m - mn) * INV_GAMMA);
    float c2 = __expf((mo - mn) * INV_GAMMA);
    sum_ew = sum_ew * c1 + so * c2;
    sum_r  = sum_r  * c1 + ro * c2;
    sum_g  = sum_g  * c1 + go * c2;
    sum_b  = sum_b  * c1 + bo * c2;
    aprod *= ao;
    m = mn;
  }

  if (s == 0) {
    int row = tileY * TILE + py;
    int col = tileX * TILE + px;
    int t = row * CROPN + col;
    float bg = __expf((EPSV - m) * INV_GAMMA);
    float inv_den = 1.0f / (sum_ew + bg);
    d_out[t] = 1.0f - aprod;              // rendered_seg
    float* dd = d_out + NPIX + t * 3;     // rendered_depth
    dd[0] = sum_r * inv_den;
    dd[1] = sum_g * inv_den;
    dd[2] = sum_b * inv_den;
  }
}

extern "C" void kernel_launch(void* const* d_in, const int* in_sizes, int n_in,
                              void* d_out, int out_size, void* d_ws, size_t ws_size,
                              hipStream_t stream) {
  const float* faces = (const float*)d_in[0];  // (1,384,3,3)
  const float* tex   = (const float*)d_in[1];  // (1,384,3,3)
  float* out = (float*)d_out;                  // 50176 seg + 150528 depth
  softras_fused<<<NTILES, 256, 0, stream>>>(faces, tex, out);
}

// Round 9
// 10.940 us; speedup vs baseline: 1.2925x; 1.2925x over previous
//
#include <hip/hip_runtime.h>
#include <math.h>

namespace {
constexpr int NFACES = 384;
constexpr int IMG    = 256;
constexpr int CROP0  = 16;
constexpr int CROPN  = 224;
constexpr int NPIX   = CROPN * CROPN;       // 50176
constexpr int TILE   = 8;                   // 8x8 pixel tiles
constexpr int TILES_X = CROPN / TILE;       // 28
constexpr int NTILES  = TILES_X * TILES_X;  // 784
constexpr int NF4     = NFACES * 9 / 4;     // 864 float4 per input array
constexpr float INV_SIGMA = 1e5f;
constexpr float INV_GAMMA = 1e5f;
constexpr float EPSV  = 1e-4f;
constexpr float NEARV = 0.1f;
constexpr float FARV  = 100.0f;
constexpr float INV_FMN = 1.0f / (FARV - NEARV);
constexpr float THRESH = 1.1512915464633e-04f;  // SIGMA*ln(1/DIST_EPS - 1)
constexpr float RADIUS = 0.0118f;               // sqrt(THRESH) + margin
}

__device__ __forceinline__ float clamp01(float x) {
  return fminf(fmaxf(x, 0.0f), 1.0f);
}

// One block = one 8x8 tile. 4 waves; each wave owns 16 pixels, 4-way face split.
// All face/tex data staged coalesced into LDS; all derived math inline (rcpf).
// (Exact revert to the round-6 kernel — best measured: 10.76 us.)
__global__ __launch_bounds__(256) void softras_fused(
    const float* __restrict__ g_faces, const float* __restrict__ g_tex,
    float* __restrict__ d_out) {
  __shared__ __align__(16) float sface[NFACES * 9];   // 13824 B
  __shared__ __align__(16) float stex[NFACES * 9];    // 13824 B
  __shared__ unsigned short slist[NFACES];            // 768 B

  int tid  = threadIdx.x;
  int w    = tid >> 6;
  int lane = tid & 63;

  // ---- coalesced raw staging ----
  {
    const float4* gf4 = reinterpret_cast<const float4*>(g_faces);
    const float4* gt4 = reinterpret_cast<const float4*>(g_tex);
    float4* sf4 = reinterpret_cast<float4*>(sface);
    float4* st4 = reinterpret_cast<float4*>(stex);
    for (int i = tid; i < NF4; i += 256) {
      sf4[i] = gf4[i];
      st4[i] = gt4[i];
    }
  }

  int tileX = blockIdx.x % TILES_X;
  int tileY = blockIdx.x / TILES_X;
  float x_lo = (2.0f * (tileX * TILE + CROP0) + 1.0f) * (1.0f / IMG) - 1.0f;
  float x_hi = x_lo + (TILE - 1) * (2.0f / IMG);
  float y_hi = (2.0f * (IMG - 1 - (tileY * TILE + CROP0)) + 1.0f) * (1.0f / IMG) - 1.0f;
  float y_lo = y_hi - (TILE - 1) * (2.0f / IMG);

  __syncthreads();

  // ---- binning from LDS: every wave computes identical ballots; wave 0
  //      writes the compacted list. L identical across waves. ----
  unsigned long long lm = (1ull << lane) - 1ull;
  int L = 0;
  #pragma unroll
  for (int r = 0; r < 6; ++r) {
    int f = r * 64 + lane;
    const float* fv = &sface[f * 9];
    float fx0 = fv[0], fy0 = fv[1];
    float fx1 = fv[3], fy1 = fv[4];
    float fx2 = fv[6], fy2 = fv[7];
    float bxmin = fminf(fx0, fminf(fx1, fx2)) - RADIUS;
    float bxmax = fmaxf(fx0, fmaxf(fx1, fx2)) + RADIUS;
    float bymin = fminf(fy0, fminf(fy1, fy2)) - RADIUS;
    float bymax = fmaxf(fy0, fmaxf(fy1, fy2)) + RADIUS;
    bool pred = (bxmin <= x_hi) && (bxmax >= x_lo) &&
                (bymin <= y_hi) && (bymax >= y_lo);
    unsigned long long bal = __ballot(pred);
    if (w == 0 && pred) slist[L + __popcll(bal & lm)] = (unsigned short)f;
    L += __popcll(bal);
  }
  __syncthreads();

  // ---- per-pixel accumulation: wave w owns pixels w*16..w*16+15;
  //      4-way face split (s) within each 16-lane pixel group ----
  int s  = lane >> 4;
  int p  = (w << 4) | (lane & 15);
  int px = p & 7, py = p >> 3;
  float qx = x_lo + px * (2.0f / IMG);
  float qy = y_hi - py * (2.0f / IMG);

  float m = EPSV;
  float sum_ew = 0.0f, sum_r = 0.0f, sum_g = 0.0f, sum_b = 0.0f;
  float aprod = 1.0f;

  for (int j = s; j < L; j += 4) {
    int f = slist[j];
    const float* fv = &sface[f * 9];
    const float* tx = &stex[f * 9];
    float x0 = fv[0], y0 = fv[1], z0 = fv[2];
    float x1 = fv[3], y1 = fv[4], z1 = fv[5];
    float x2 = fv[6], y2 = fv[7], z2 = fv[8];

    float den = (y1 - y2) * (x0 - x2) + (x2 - x1) * (y0 - y2);
    if (fabsf(den) < 1e-10f) den = (den < 0.0f) ? -1e-10f : 1e-10f;
    float dinv = __builtin_amdgcn_rcpf(den);

    float qa2x = qx - x2, qa2y = qy - y2;
    float w0 = ((y1 - y2) * qa2x + (x2 - x1) * qa2y) * dinv;
    float w1 = ((y2 - y0) * qa2x + (x0 - x2) * qa2y) * dinv;
    float w2 = 1.0f - w0 - w1;
    bool inside = (w0 >= 0.0f) && (w1 >= 0.0f) && (w2 >= 0.0f);

    float qa0x = qx - x0, qa0y = qy - y0;
    float qa1x = qx - x1, qa1y = qy - y1;

    float ex = x1 - x0, ey = y1 - y0;
    float il = __builtin_amdgcn_rcpf(fmaxf(ex * ex + ey * ey, 1e-12f));
    float tt = clamp01((qa0x * ex + qa0y * ey) * il);
    float dx = qa0x - tt * ex, dy = qa0y - tt * ey;
    float d2min = dx * dx + dy * dy;

    ex = x2 - x1; ey = y2 - y1;
    il = __builtin_amdgcn_rcpf(fmaxf(ex * ex + ey * ey, 1e-12f));
    tt = clamp01((qa1x * ex + qa1y * ey) * il);
    dx = qa1x - tt * ex; dy = qa1y - tt * ey;
    d2min = fminf(d2min, dx * dx + dy * dy);

    ex = x0 - x2; ey = y0 - y2;
    il = __builtin_amdgcn_rcpf(fmaxf(ex * ex + ey * ey, 1e-12f));
    tt = clamp01((qa2x * ex + qa2y * ey) * il);
    dx = qa2x - tt * ex; dy = qa2y - tt * ey;
    d2min = fminf(d2min, dx * dx + dy * dy);

    bool contrib = inside || (d2min <= THRESH);

    float wc0 = clamp01(w0), wc1 = clamp01(w1), wc2 = clamp01(w2);
    float invs = __builtin_amdgcn_rcpf(fmaxf(wc0 + wc1 + wc2, 1e-12f));
    wc0 *= invs; wc1 *= invs; wc2 *= invs;

    float zden = wc0 * __builtin_amdgcn_rcpf(z0) +
                 wc1 * __builtin_amdgcn_rcpf(z1) +
                 wc2 * __builtin_amdgcn_rcpf(z2);
    float zp = __builtin_amdgcn_rcpf(fmaxf(zden, 1e-12f));
    bool valid = contrib && (zp >= NEARV) && (zp <= FARV);
    float zn = (FARV - zp) * INV_FMN;
    float zns = valid ? zn : 0.0f;

    float e = __expf(-d2min * INV_SIGMA);
    float r1pe = __builtin_amdgcn_rcpf(1.0f + e);
    float Dp = inside ? r1pe : e * r1pe;   // stable sigmoid

    float mnew = fmaxf(m, zns);
    float cor = __expf((m - mnew) * INV_GAMMA);
    float ew = valid ? Dp * __expf((zns - mnew) * INV_GAMMA) : 0.0f;

    float cr = wc0 * tx[0] + wc1 * tx[3] + wc2 * tx[6];
    float cg = wc0 * tx[1] + wc1 * tx[4] + wc2 * tx[7];
    float cb = wc0 * tx[2] + wc1 * tx[5] + wc2 * tx[8];

    sum_ew = sum_ew * cor + ew;
    sum_r  = sum_r  * cor + ew * cr;
    sum_g  = sum_g  * cor + ew * cg;
    sum_b  = sum_b  * cor + ew * cb;
    aprod *= contrib ? (1.0f - Dp) : 1.0f;
    m = mnew;
  }

  // ---- merge the 4 face sub-chunks (lane bits 4..5) ----
  #pragma unroll
  for (int mask = 16; mask <= 32; mask <<= 1) {
    float mo = __shfl_xor(m, mask);
    float so = __shfl_xor(sum_ew, mask);
    float ro = __shfl_xor(sum_r, mask);
    float go = __shfl_xor(sum_g, mask);
    float bo = __shfl_xor(sum_b, mask);
    float ao = __shfl_xor(aprod, mask);
    float mn = fmaxf(m, mo);
    float c1 = __expf((m - mn) * INV_GAMMA);
    float c2 = __expf((mo - mn) * INV_GAMMA);
    sum_ew = sum_ew * c1 + so * c2;
    sum_r  = sum_r  * c1 + ro * c2;
    sum_g  = sum_g  * c1 + go * c2;
    sum_b  = sum_b  * c1 + bo * c2;
    aprod *= ao;
    m = mn;
  }

  if (s == 0) {
    int row = tileY * TILE + py;
    int col = tileX * TILE + px;
    int t = row * CROPN + col;
    float bg = __expf((EPSV - m) * INV_GAMMA);
    float inv_den = 1.0f / (sum_ew + bg);
    d_out[t] = 1.0f - aprod;              // rendered_seg
    float* dd = d_out + NPIX + t * 3;     // rendered_depth
    dd[0] = sum_r * inv_den;
    dd[1] = sum_g * inv_den;
    dd[2] = sum_b * inv_den;
  }
}

extern "C" void kernel_launch(void* const* d_in, const int* in_sizes, int n_in,
                              void* d_out, int out_size, void* d_ws, size_t ws_size,
                              hipStream_t stream) {
  const float* faces = (const float*)d_in[0];  // (1,384,3,3)
  const float* tex   = (const float*)d_in[1];  // (1,384,3,3)
  float* out = (float*)d_out;                  // 50176 seg + 150528 depth
  softras_fused<<<NTILES, 256, 0, stream>>>(faces, tex, out);
}